// Round 3
// baseline (23322.359 us; speedup 1.0000x reference)
//
#include <hip/hip_runtime.h>

#define NB 32
#define NT 512
#define NI 512
#define NH 512
#define NG 2048
#define GH (NG*NH)
#define BTH ((size_t)NB*NT*NH)   // 8388608
#define BH  (NB*NH)              // 16384

typedef unsigned int uint;
typedef _Float16 v2h __attribute__((ext_vector_type(2)));

// ---- ws layout (bytes) ----
#define OFF_XPROJ 0
#define SZ_XPROJ  ((size_t)NB*NT*NG*2)            // 64 MB  x_proj bf16 [B][T][G]
#define OFF_BIAS  (OFF_XPROJ + SZ_XPROJ)
#define SZ_BIAS   ((size_t)NB*NG*4)               // 256 KB fp32 bias [B][G]
#define OFF_HG    (OFF_BIAS + SZ_BIAS)
#define SZ_HG     ((size_t)2*NB*NH*4)             // 128 KB double-buffered fp32 h
#define OFF_CNT   (OFF_HG + SZ_HG)
#define SZ_CNT    ((size_t)NB*32*4)               // barrier counters, 128B stride

__device__ __forceinline__ float bf2f(unsigned short u) {
    union { uint i; float f; } v; v.i = ((uint)u) << 16; return v.f;
}
__device__ __forceinline__ unsigned short f2bf(float f) {
    union { uint i; float f; } v; v.f = f;
    uint r = v.i + 0x7FFFu + ((v.i >> 16) & 1u);
    return (unsigned short)(r >> 16);
}
__device__ __forceinline__ uint pkf16(float a, float b) {
    auto p = __builtin_amdgcn_cvt_pkrtz(a, b);   // __fp16 ext_vector(2)
    return __builtin_bit_cast(uint, p);
}
__device__ __forceinline__ float dot2(uint wu, uint hu, float c) {
#if __has_builtin(__builtin_amdgcn_fdot2)
    return __builtin_amdgcn_fdot2(__builtin_bit_cast(v2h, wu),
                                  __builtin_bit_cast(v2h, hu), c, false);
#else
    v2h a = __builtin_bit_cast(v2h, wu), b = __builtin_bit_cast(v2h, hu);
    return c + (float)a[0] * (float)b[0] + (float)a[1] * (float)b[1];
#endif
}
// z = clip(1.2*sigmoid(1.5*(log(eps)-log(1-eps)+m)) - 0.1, 0, 1)
__device__ __forceinline__ float gate_z(float eps, float m) {
    float u = (__logf(eps) - __logf(1.0f - eps) + m) * 1.5f;
    float y = 1.0f / (1.0f + __expf(-u));
    float z = fmaf(y, 1.2f, -0.1f);
    return fminf(fmaxf(z, 0.0f), 1.0f);
}
__device__ __forceinline__ float sigmoidf_(float x) {
    return 1.0f / (1.0f + __expf(-x));
}
__device__ __forceinline__ float tanhf_(float x) {
    // 1 - 2/(e^{2x}+1); __expf saturates -> correct +-1 tails
    return 1.0f - 2.0f / (__expf(2.0f * x) + 1.0f);
}

// ---------- bias[b][g] ----------
__global__ __launch_bounds__(256) void k_bias(
    const float* __restrict__ eb1, const float* __restrict__ eb2,
    const float* __restrict__ mb1, const float* __restrict__ mb2,
    const float* __restrict__ b1, const float* __restrict__ b2,
    float* __restrict__ bias) {
    int idx = blockIdx.x * 256 + threadIdx.x;
    int g = idx & (NG - 1);
    bias[idx] = gate_z(eb1[idx], mb1[g]) * b1[g] + gate_z(eb2[idx], mb2[g]) * b2[g];
}

// ---------- x_proj[b][t][g] (gating of Wih fused) ----------
__global__ __launch_bounds__(256) void k_xproj(
    const float* __restrict__ seq, const float* __restrict__ eps_ih,
    const float* __restrict__ mask_ih, const float* __restrict__ w_ih,
    const float* __restrict__ bias, unsigned short* __restrict__ xproj) {
    __shared__ float As[128 * 33];
    __shared__ float Ws[32 * 68];
    int g0 = blockIdx.x * 64;
    int t0 = blockIdx.y * 128;
    int b  = blockIdx.z;
    int tid = threadIdx.x;
    int gq = tid & 15;
    int rq = tid >> 4;
    float acc[4][8];
#pragma unroll
    for (int c = 0; c < 4; ++c)
#pragma unroll
        for (int k = 0; k < 8; ++k) acc[c][k] = 0.0f;

    for (int i0 = 0; i0 < NI; i0 += 32) {
        __syncthreads();
#pragma unroll
        for (int k = 0; k < 4; ++k) {
            int e = (tid + (k << 8)) << 2;
            int r = e >> 5, c = e & 31;
            float4 v = *(const float4*)(seq + (b * NT + t0 + r) * NI + i0 + c);
            As[r * 33 + c    ] = v.x;
            As[r * 33 + c + 1] = v.y;
            As[r * 33 + c + 2] = v.z;
            As[r * 33 + c + 3] = v.w;
        }
#pragma unroll
        for (int k = 0; k < 2; ++k) {
            int e = (tid + (k << 8)) << 2;
            int gr = e >> 5, c = e & 31;
            int mo = (g0 + gr) * NI + i0 + c;
            int eo = b * GH + mo;
            float4 ev = *(const float4*)(eps_ih + eo);
            float4 mv = *(const float4*)(mask_ih + mo);
            float4 wv = *(const float4*)(w_ih + mo);
            Ws[(c    ) * 68 + gr] = gate_z(ev.x, mv.x) * wv.x;
            Ws[(c + 1) * 68 + gr] = gate_z(ev.y, mv.y) * wv.y;
            Ws[(c + 2) * 68 + gr] = gate_z(ev.z, mv.z) * wv.z;
            Ws[(c + 3) * 68 + gr] = gate_z(ev.w, mv.w) * wv.w;
        }
        __syncthreads();
#pragma unroll 4
        for (int i = 0; i < 32; ++i) {
            float4 wv = *(const float4*)&Ws[i * 68 + (gq << 2)];
#pragma unroll
            for (int k = 0; k < 8; ++k) {
                float av = As[(rq + (k << 4)) * 33 + i];
                acc[0][k] = fmaf(wv.x, av, acc[0][k]);
                acc[1][k] = fmaf(wv.y, av, acc[1][k]);
                acc[2][k] = fmaf(wv.z, av, acc[2][k]);
                acc[3][k] = fmaf(wv.w, av, acc[3][k]);
            }
        }
    }
    float bs[4];
#pragma unroll
    for (int c = 0; c < 4; ++c) bs[c] = bias[b * NG + g0 + (gq << 2) + c];
#pragma unroll
    for (int k = 0; k < 8; ++k) {
        int r = t0 + rq + (k << 4);
        unsigned short* op = xproj + (b * NT + r) * NG + g0 + (gq << 2);
        union { uint2 v; unsigned short s[4]; } o;
        o.s[0] = f2bf(acc[0][k] + bs[0]);
        o.s[1] = f2bf(acc[1][k] + bs[1]);
        o.s[2] = f2bf(acc[2][k] + bs[2]);
        o.s[3] = f2bf(acc[3][k] + bs[3]);
        *(uint2*)op = o.v;
    }
}

// ---------- Persistent recurrence: weights resident in VGPRs ----------
// grid 256 x 1024: block bb -> batch b=bb>>3, j-slice (bb&7)*64.
// thread: wave w (16/block), lane l; j = slice*64 + w*4 + (l>>4); kg = l&15.
// Owns rows {q*512+j} x k in [kg*32, kg*32+32) as 64 packed-f16 uints.
__global__ __launch_bounds__(1024) void k_recur(
    const float* __restrict__ eps, const float* __restrict__ mask,
    const float* __restrict__ w, const unsigned short* __restrict__ xproj,
    float* __restrict__ hglob, int* __restrict__ cnt, float* __restrict__ out) {
    __shared__ uint hsh[256];   // h_t as packed f16 pairs
    int bb = blockIdx.x;
    int b = bb >> 3, slice = bb & 7;
    int tid = threadIdx.x;
    int wv = tid >> 6, lane = tid & 63;
    int jj = lane >> 4, kg = lane & 15;
    int j = (slice << 6) + (wv << 2) + jj;
    bool leader = (kg == 0);

    // ---- one-time: load + gate + f16-pack weights into registers ----
    uint wreg[4][16];
#pragma unroll
    for (int q = 0; q < 4; ++q) {
        size_t row = (size_t)((q << 9) + j);
        size_t off = row * NH + (kg << 5);
        const float2* ep = (const float2*)(eps + (size_t)b * GH + off);
        const float2* mp = (const float2*)(mask + off);
        const float2* wp = (const float2*)(w + off);
#pragma unroll
        for (int u = 0; u < 16; ++u) {
            float2 e = ep[u], m = mp[u], ww = wp[u];
            wreg[q][u] = pkf16(gate_z(e.x, m.x) * ww.x,
                               gate_z(e.y, m.y) * ww.y);
        }
    }

    float c = 0.0f;
    for (int t = 0; t < NT; ++t) {
        // stage h_t (fp32 global, agent-coherent) -> packed f16 LDS
        const float* hsrc = hglob + (((t & 1) * NB + b) << 9);
        if (tid < 256) {
            float a0 = __hip_atomic_load(hsrc + 2 * tid,     __ATOMIC_RELAXED, __HIP_MEMORY_SCOPE_AGENT);
            float a1 = __hip_atomic_load(hsrc + 2 * tid + 1, __ATOMIC_RELAXED, __HIP_MEMORY_SCOPE_AGENT);
            hsh[tid] = pkf16(a0, a1);
        }
        float xp0, xp1, xp2, xp3;
        if (leader) {
            const unsigned short* xq = xproj + ((size_t)(b * NT + t) << 11) + j;
            xp0 = bf2f(xq[0]); xp1 = bf2f(xq[512]);
            xp2 = bf2f(xq[1024]); xp3 = bf2f(xq[1536]);
        }
        __syncthreads();

        float a0 = 0.f, a1 = 0.f, a2 = 0.f, a3 = 0.f;
#pragma unroll
        for (int r = 0; r < 4; ++r) {
            uint4 hv = *(const uint4*)&hsh[(kg << 4) + (r << 2)];
            uint hu[4] = {hv.x, hv.y, hv.z, hv.w};
#pragma unroll
            for (int u = 0; u < 4; ++u) {
                a0 = dot2(wreg[0][(r << 2) + u], hu[u], a0);
                a1 = dot2(wreg[1][(r << 2) + u], hu[u], a1);
                a2 = dot2(wreg[2][(r << 2) + u], hu[u], a2);
                a3 = dot2(wreg[3][(r << 2) + u], hu[u], a3);
            }
        }
#pragma unroll
        for (int off = 8; off > 0; off >>= 1) {
            a0 += __shfl_xor(a0, off);
            a1 += __shfl_xor(a1, off);
            a2 += __shfl_xor(a2, off);
            a3 += __shfl_xor(a3, off);
        }
        if (leader) {
            float gi = a0 + xp0, gf = a1 + xp1, gg = a2 + xp2, go = a3 + xp3;
            c = fmaf(sigmoidf_(gf), c, sigmoidf_(gi) * tanhf_(gg));
            float h = sigmoidf_(go) * tanhf_(c);
            out[((size_t)(b * NT + t) << 9) + j] = h;
            float* hdst = hglob + ((((t + 1) & 1) * NB + b) << 9);
            __hip_atomic_store(hdst + j, h, __ATOMIC_RELEASE, __HIP_MEMORY_SCOPE_AGENT);
            if (t == NT - 1) {
                out[BTH + (size_t)(b << 9) + j] = h;
                out[BTH + BH + (size_t)(b << 9) + j] = c;
            }
        }
        __syncthreads();  // all stores issued + LDS reads done
        if (tid == 0) {
            __hip_atomic_fetch_add(&cnt[b << 5], 1, __ATOMIC_ACQ_REL, __HIP_MEMORY_SCOPE_AGENT);
            int target = (t + 1) << 3;
            while (__hip_atomic_load(&cnt[b << 5], __ATOMIC_ACQUIRE, __HIP_MEMORY_SCOPE_AGENT) < target)
                __builtin_amdgcn_s_sleep(1);
        }
        __syncthreads();
    }
}

extern "C" void kernel_launch(void* const* d_in, const int* in_sizes, int n_in,
                              void* d_out, int out_size, void* d_ws, size_t ws_size,
                              hipStream_t stream) {
    const float* seq      = (const float*)d_in[0];
    const float* w_ih     = (const float*)d_in[1];
    const float* w_hh     = (const float*)d_in[2];
    const float* b_ih     = (const float*)d_in[3];
    const float* b_hh     = (const float*)d_in[4];
    const float* mask_ih  = (const float*)d_in[5];
    const float* mask_hh  = (const float*)d_in[6];
    const float* mask_bih = (const float*)d_in[7];
    const float* mask_bhh = (const float*)d_in[8];
    const float* eps_ih   = (const float*)d_in[9];
    const float* eps_hh   = (const float*)d_in[10];
    const float* eps_bih  = (const float*)d_in[11];
    const float* eps_bhh  = (const float*)d_in[12];

    char* ws = (char*)d_ws;
    unsigned short* xproj = (unsigned short*)(ws + OFF_XPROJ);
    float* bias  = (float*)(ws + OFF_BIAS);
    float* hglob = (float*)(ws + OFF_HG);
    int*   cnt   = (int*)(ws + OFF_CNT);
    float* out   = (float*)d_out;

    // zero h_0 (buffer 0) and barrier counters (ws arrives poisoned 0xAA)
    (void)hipMemsetAsync(hglob, 0, (size_t)NB * NH * 4, stream);
    (void)hipMemsetAsync(cnt, 0, SZ_CNT, stream);

    k_bias<<<dim3(256), dim3(256), 0, stream>>>(eps_bih, eps_bhh, mask_bih, mask_bhh,
                                                b_ih, b_hh, bias);
    k_xproj<<<dim3(NG / 64, NT / 128, NB), dim3(256), 0, stream>>>(
        seq, eps_ih, mask_ih, w_ih, bias, xproj);
    k_recur<<<dim3(256), dim3(1024), 0, stream>>>(
        eps_hh, mask_hh, w_hh, xproj, hglob, cnt, out);
}

// Round 4
// 5810.365 us; speedup vs baseline: 4.0139x; 4.0139x over previous
//
#include <hip/hip_runtime.h>

#define NB 32
#define NT 512
#define NI 512
#define NH 512
#define NG 2048
#define GH (NG*NH)
#define BTH ((size_t)NB*NT*NH)   // 8388608
#define BH  (NB*NH)              // 16384

typedef unsigned int uint;
typedef unsigned long long u64;
typedef _Float16 v2h __attribute__((ext_vector_type(2)));

// ---- ws layout (bytes) ----
#define OFF_XPROJ 0
#define SZ_XPROJ  ((size_t)NB*NT*NG*2)            // 64 MB  x_proj bf16 [B][T][G]
#define OFF_BIAS  (OFF_XPROJ + SZ_XPROJ)
#define SZ_BIAS   ((size_t)NB*NG*4)               // 256 KB fp32 bias [B][G]
#define OFF_HG    (OFF_BIAS + SZ_BIAS)
#define SZ_HG     ((size_t)2*NB*NH*4)             // 128 KB double-buffered fp32 h
#define OFF_FLG   (OFF_HG + SZ_HG)
#define SZ_FLG    ((size_t)NB*8*32*4)             // 32 KB: flag per block, 128B stride

__device__ __forceinline__ float bf2f(unsigned short u) {
    union { uint i; float f; } v; v.i = ((uint)u) << 16; return v.f;
}
__device__ __forceinline__ unsigned short f2bf(float f) {
    union { uint i; float f; } v; v.f = f;
    uint r = v.i + 0x7FFFu + ((v.i >> 16) & 1u);
    return (unsigned short)(r >> 16);
}
__device__ __forceinline__ uint pkf16(float a, float b) {
    auto p = __builtin_amdgcn_cvt_pkrtz(a, b);   // __fp16 ext_vector(2)
    return __builtin_bit_cast(uint, p);
}
__device__ __forceinline__ float dot2(uint wu, uint hu, float c) {
#if __has_builtin(__builtin_amdgcn_fdot2)
    return __builtin_amdgcn_fdot2(__builtin_bit_cast(v2h, wu),
                                  __builtin_bit_cast(v2h, hu), c, false);
#else
    v2h a = __builtin_bit_cast(v2h, wu), b = __builtin_bit_cast(v2h, hu);
    return c + (float)a[0] * (float)b[0] + (float)a[1] * (float)b[1];
#endif
}
// z = clip(1.2*sigmoid(1.5*(log(eps)-log(1-eps)+m)) - 0.1, 0, 1)
__device__ __forceinline__ float gate_z(float eps, float m) {
    float u = (__logf(eps) - __logf(1.0f - eps) + m) * 1.5f;
    float y = 1.0f / (1.0f + __expf(-u));
    float z = fmaf(y, 1.2f, -0.1f);
    return fminf(fmaxf(z, 0.0f), 1.0f);
}
__device__ __forceinline__ float sigmoidf_(float x) {
    return 1.0f / (1.0f + __expf(-x));
}
__device__ __forceinline__ float tanhf_(float x) {
    return 1.0f - 2.0f / (__expf(2.0f * x) + 1.0f);
}
// LDS swizzle for hsh: 2-way max bank aliasing for 16B reads (free per m136)
__device__ __forceinline__ int hswz(int kg, int r, int u) {
    return (kg << 4) + (((r + (kg >> 1)) & 3) << 2) + u;
}

// ---------- bias[b][g] ----------
__global__ __launch_bounds__(256) void k_bias(
    const float* __restrict__ eb1, const float* __restrict__ eb2,
    const float* __restrict__ mb1, const float* __restrict__ mb2,
    const float* __restrict__ b1, const float* __restrict__ b2,
    float* __restrict__ bias) {
    int idx = blockIdx.x * 256 + threadIdx.x;
    int g = idx & (NG - 1);
    bias[idx] = gate_z(eb1[idx], mb1[g]) * b1[g] + gate_z(eb2[idx], mb2[g]) * b2[g];
}

// ---------- x_proj[b][t][g] (gating of Wih fused) ----------
__global__ __launch_bounds__(256) void k_xproj(
    const float* __restrict__ seq, const float* __restrict__ eps_ih,
    const float* __restrict__ mask_ih, const float* __restrict__ w_ih,
    const float* __restrict__ bias, unsigned short* __restrict__ xproj) {
    __shared__ float As[128 * 33];
    __shared__ float Ws[32 * 68];
    int g0 = blockIdx.x * 64;
    int t0 = blockIdx.y * 128;
    int b  = blockIdx.z;
    int tid = threadIdx.x;
    int gq = tid & 15;
    int rq = tid >> 4;
    float acc[4][8];
#pragma unroll
    for (int c = 0; c < 4; ++c)
#pragma unroll
        for (int k = 0; k < 8; ++k) acc[c][k] = 0.0f;

    for (int i0 = 0; i0 < NI; i0 += 32) {
        __syncthreads();
#pragma unroll
        for (int k = 0; k < 4; ++k) {
            int e = (tid + (k << 8)) << 2;
            int r = e >> 5, c = e & 31;
            float4 v = *(const float4*)(seq + (b * NT + t0 + r) * NI + i0 + c);
            As[r * 33 + c    ] = v.x;
            As[r * 33 + c + 1] = v.y;
            As[r * 33 + c + 2] = v.z;
            As[r * 33 + c + 3] = v.w;
        }
#pragma unroll
        for (int k = 0; k < 2; ++k) {
            int e = (tid + (k << 8)) << 2;
            int gr = e >> 5, c = e & 31;
            int mo = (g0 + gr) * NI + i0 + c;
            int eo = b * GH + mo;
            float4 ev = *(const float4*)(eps_ih + eo);
            float4 mv = *(const float4*)(mask_ih + mo);
            float4 wv = *(const float4*)(w_ih + mo);
            Ws[(c    ) * 68 + gr] = gate_z(ev.x, mv.x) * wv.x;
            Ws[(c + 1) * 68 + gr] = gate_z(ev.y, mv.y) * wv.y;
            Ws[(c + 2) * 68 + gr] = gate_z(ev.z, mv.z) * wv.z;
            Ws[(c + 3) * 68 + gr] = gate_z(ev.w, mv.w) * wv.w;
        }
        __syncthreads();
#pragma unroll 4
        for (int i = 0; i < 32; ++i) {
            float4 wv = *(const float4*)&Ws[i * 68 + (gq << 2)];
#pragma unroll
            for (int k = 0; k < 8; ++k) {
                float av = As[(rq + (k << 4)) * 33 + i];
                acc[0][k] = fmaf(wv.x, av, acc[0][k]);
                acc[1][k] = fmaf(wv.y, av, acc[1][k]);
                acc[2][k] = fmaf(wv.z, av, acc[2][k]);
                acc[3][k] = fmaf(wv.w, av, acc[3][k]);
            }
        }
    }
    float bs[4];
#pragma unroll
    for (int c = 0; c < 4; ++c) bs[c] = bias[b * NG + g0 + (gq << 2) + c];
#pragma unroll
    for (int k = 0; k < 8; ++k) {
        int r = t0 + rq + (k << 4);
        unsigned short* op = xproj + (b * NT + r) * NG + g0 + (gq << 2);
        union { uint2 v; unsigned short s[4]; } o;
        o.s[0] = f2bf(acc[0][k] + bs[0]);
        o.s[1] = f2bf(acc[1][k] + bs[1]);
        o.s[2] = f2bf(acc[2][k] + bs[2]);
        o.s[3] = f2bf(acc[3][k] + bs[3]);
        *(uint2*)op = o.v;
    }
}

// ---------- Persistent recurrence: weights resident in VGPRs ----------
// 256 blocks x 1024 threads, 1 block/CU (launch_bounds(1024,4) -> 128 VGPR cap).
// block bb: batch b=bb>>3, j-slice (bb&7)*64. thread: wave wv, lane l;
// j = slice*64 + wv*4 + (l>>4); kg = l&15 owns k in [kg*32, kg*32+32).
__global__ __launch_bounds__(1024, 4) void k_recur(
    const float* __restrict__ eps, const float* __restrict__ mask,
    const float* __restrict__ w, const unsigned short* __restrict__ xproj,
    float* __restrict__ hglob, int* __restrict__ flg, float* __restrict__ out) {
    __shared__ uint hsh[256];   // h_t as packed f16 pairs (swizzled)
    int bb = blockIdx.x;
    int b = bb >> 3, slice = bb & 7;
    int tid = threadIdx.x;
    int wv = tid >> 6, lane = tid & 63;
    int jj = lane >> 4, kg = lane & 15;
    int j = (slice << 6) + (wv << 2) + jj;
    bool leader = (kg == 0);

    // ---- one-time: load + gate + f16-pack weights into registers ----
    uint wreg[4][16];
#pragma unroll
    for (int q = 0; q < 4; ++q) {
        size_t off = (size_t)((q << 9) + j) * NH + (kg << 5);
        const float2* ep = (const float2*)(eps + (size_t)b * GH + off);
        const float2* mp = (const float2*)(mask + off);
        const float2* wp = (const float2*)(w + off);
#pragma unroll
        for (int u = 0; u < 16; ++u) {
            float2 e = ep[u], m = mp[u], ww = wp[u];
            wreg[q][u] = pkf16(gate_z(e.x, m.x) * ww.x,
                               gate_z(e.y, m.y) * ww.y);
        }
    }

    // prefetch xproj for t=0
    float xp0 = 0.f, xp1 = 0.f, xp2 = 0.f, xp3 = 0.f;
    if (leader) {
        const unsigned short* xq = xproj + ((size_t)(b * NT) << 11) + j;
        xp0 = bf2f(xq[0]); xp1 = bf2f(xq[512]);
        xp2 = bf2f(xq[1024]); xp3 = bf2f(xq[1536]);
    }

    float c = 0.0f;
    for (int t = 0; t < NT; ++t) {
        // stage h_t (fp32 global, agent-coherent) -> packed f16 LDS, swizzled
        if (tid < 256) {
            const u64* hsrc = (const u64*)(hglob + (((t & 1) * NB + b) << 9));
            u64 v = __hip_atomic_load(hsrc + tid, __ATOMIC_RELAXED, __HIP_MEMORY_SCOPE_AGENT);
            union { uint i; float f; } lo, hi;
            lo.i = (uint)v; hi.i = (uint)(v >> 32);
            int pkg = tid >> 4, pr = (tid >> 2) & 3, pu = tid & 3;
            hsh[hswz(pkg, pr, pu)] = pkf16(lo.f, hi.f);
        }
        __syncthreads();

        float a0 = 0.f, a1 = 0.f, a2 = 0.f, a3 = 0.f;
#pragma unroll
        for (int r = 0; r < 4; ++r) {
            uint4 hv = *(const uint4*)&hsh[hswz(kg, r, 0)];
            uint hu[4] = {hv.x, hv.y, hv.z, hv.w};
#pragma unroll
            for (int u = 0; u < 4; ++u) {
                a0 = dot2(wreg[0][(r << 2) + u], hu[u], a0);
                a1 = dot2(wreg[1][(r << 2) + u], hu[u], a1);
                a2 = dot2(wreg[2][(r << 2) + u], hu[u], a2);
                a3 = dot2(wreg[3][(r << 2) + u], hu[u], a3);
            }
        }
#pragma unroll
        for (int off = 8; off > 0; off >>= 1) {
            a0 += __shfl_xor(a0, off);
            a1 += __shfl_xor(a1, off);
            a2 += __shfl_xor(a2, off);
            a3 += __shfl_xor(a3, off);
        }
        if (leader) {
            float gi = a0 + xp0, gf = a1 + xp1, gg = a2 + xp2, go = a3 + xp3;
            c = fmaf(sigmoidf_(gf), c, sigmoidf_(gi) * tanhf_(gg));
            float h = sigmoidf_(go) * tanhf_(c);
            out[((size_t)(b * NT + t) << 9) + j] = h;
            float* hdst = hglob + ((((t + 1) & 1) * NB + b) << 9);
            __hip_atomic_store(hdst + j, h, __ATOMIC_RELAXED, __HIP_MEMORY_SCOPE_AGENT);
            if (t == NT - 1) {
                out[BTH + (size_t)(b << 9) + j] = h;
                out[BTH + BH + (size_t)(b << 9) + j] = c;
            }
            // prefetch xproj for t+1 (independent of barrier)
            if (t + 1 < NT) {
                const unsigned short* xq = xproj + ((size_t)(b * NT + t + 1) << 11) + j;
                xp0 = bf2f(xq[0]); xp1 = bf2f(xq[512]);
                xp2 = bf2f(xq[1024]); xp3 = bf2f(xq[1536]);
            }
        }
        __syncthreads();  // all h stores drained (vmcnt 0) + LDS reads done
        // distributed flag barrier over the 8 blocks of batch b
        if (tid == 0)
            __hip_atomic_store(&flg[(b * 8 + slice) * 32], t + 1,
                               __ATOMIC_RELEASE, __HIP_MEMORY_SCOPE_AGENT);
        if (tid < 8) {
            while (__hip_atomic_load(&flg[(b * 8 + tid) * 32],
                                     __ATOMIC_ACQUIRE, __HIP_MEMORY_SCOPE_AGENT) < t + 1)
                __builtin_amdgcn_s_sleep(1);
        }
        __syncthreads();
    }
}

extern "C" void kernel_launch(void* const* d_in, const int* in_sizes, int n_in,
                              void* d_out, int out_size, void* d_ws, size_t ws_size,
                              hipStream_t stream) {
    const float* seq      = (const float*)d_in[0];
    const float* w_ih     = (const float*)d_in[1];
    const float* w_hh     = (const float*)d_in[2];
    const float* b_ih     = (const float*)d_in[3];
    const float* b_hh     = (const float*)d_in[4];
    const float* mask_ih  = (const float*)d_in[5];
    const float* mask_hh  = (const float*)d_in[6];
    const float* mask_bih = (const float*)d_in[7];
    const float* mask_bhh = (const float*)d_in[8];
    const float* eps_ih   = (const float*)d_in[9];
    const float* eps_hh   = (const float*)d_in[10];
    const float* eps_bih  = (const float*)d_in[11];
    const float* eps_bhh  = (const float*)d_in[12];

    char* ws = (char*)d_ws;
    unsigned short* xproj = (unsigned short*)(ws + OFF_XPROJ);
    float* bias  = (float*)(ws + OFF_BIAS);
    float* hglob = (float*)(ws + OFF_HG);
    int*   flg   = (int*)(ws + OFF_FLG);
    float* out   = (float*)d_out;

    // zero h_0 (buffer 0) and flags (ws arrives poisoned 0xAA)
    (void)hipMemsetAsync(hglob, 0, (size_t)NB * NH * 4, stream);
    (void)hipMemsetAsync(flg, 0, SZ_FLG, stream);

    k_bias<<<dim3(256), dim3(256), 0, stream>>>(eps_bih, eps_bhh, mask_bih, mask_bhh,
                                                b_ih, b_hh, bias);
    k_xproj<<<dim3(NG / 64, NT / 128, NB), dim3(256), 0, stream>>>(
        seq, eps_ih, mask_ih, w_ih, bias, xproj);
    k_recur<<<dim3(256), dim3(1024), 0, stream>>>(
        eps_hh, mask_hh, w_hh, xproj, hglob, flg, out);
}